// Round 8
// baseline (1122.610 us; speedup 1.0000x reference)
//
#include <hip/hip_runtime.h>

#define N_NODES 100000
#define N_EDGES 1600000
#define HID 128
#define SCAN_N (N_NODES*4)
#define NB1 ((SCAN_N + 1023) / 1024)
#define ZERO_IDX (N_NODES*4)   // gather index of the zero pad row in Y

#define EB 8192                // edges per block in bucket pipeline
#define NBLKA ((N_EDGES + EB - 1) / EB)          // 196
#define BSH 9                  // 512 nodes per bucket
#define NBUCK ((N_NODES + (1<<BSH) - 1) >> BSH)  // 196
#define N2 (NBUCK * NBLKA)
#define NB2 ((N2 + 1023) / 1024)

typedef __attribute__((ext_vector_type(8))) short short8;
typedef __attribute__((ext_vector_type(4))) float float4v;
typedef __attribute__((ext_vector_type(4))) int int4v;
typedef __attribute__((ext_vector_type(2))) unsigned int uint2v;
typedef unsigned short ushort_t;
typedef unsigned int uint_t;

__device__ __forceinline__ float bits2f(uint_t u){ union{uint_t u; float f;} x; x.u=u; return x.f; }
__device__ __forceinline__ float b2f(ushort_t u){ return bits2f(((uint_t)u)<<16); }
__device__ __forceinline__ ushort_t f2b(float f){
  union{float f; uint_t u;} x; x.f=f;
  uint_t r = x.u + 0x7fffu + ((x.u>>16)&1u);
  return (ushort_t)(r>>16);
}
__device__ __forceinline__ float sigm(float x){ return 1.0f/(1.0f+__expf(-x)); }
__device__ __forceinline__ float tanh_f(float x){
  float t=__expf(-2.0f*fabsf(x)); float y=(1.0f-t)/(1.0f+t); return x>=0.f? y : -y;
}
__device__ __forceinline__ int imin(int a, int b){ return a < b ? a : b; }

// ---------------- preprocessing ----------------

// WY[g][d] = W_edge flat (g = t*128+o), [512][128]
// W2[512][256]: combined GRU weights; row n -> gate j=(n>>4)&3 (0:r 1:z 2:inn 3:hn),
// output col c = ((n>>6)<<4)|(n&15); K: [0,128)=a-side (W_ih), [128,256)=h-side (W_hh).
__global__ void prep_weights(const float* __restrict__ W_edge, const float* __restrict__ W_ih,
                             const float* __restrict__ W_hh, ushort_t* __restrict__ WY,
                             ushort_t* __restrict__ W2){
  int i = blockIdx.x*256 + threadIdx.x;
  if (i < 65536){
    WY[i] = f2b(W_edge[i]);
  } else if (i < 65536 + 131072){
    int i2 = i - 65536;
    int n = i2 >> 8, k = i2 & 255;
    int j = (n >> 4) & 3;
    int c = ((n >> 6) << 4) | (n & 15);
    float v;
    if (j < 2)       v = (k < 128) ? W_ih[(j*128 + c)*128 + k] : W_hh[(j*128 + c)*128 + (k-128)];
    else if (j == 2) v = (k < 128) ? W_ih[(256 + c)*128 + k] : 0.0f;
    else             v = (k >= 128) ? W_hh[(256 + c)*128 + (k-128)] : 0.0f;
    W2[n*256 + k] = f2b(v);
  }
}

// etype argmax, pack (src<<2)|t, histogram cnt[dst*4+t] and per-block bucket hist
__global__ void edge_pass1(const int* __restrict__ eidx, const float* __restrict__ efeat,
                           int* __restrict__ packed, int* __restrict__ cnt,
                           int* __restrict__ bcntT){
  __shared__ int hist[NBUCK];
  int tid = threadIdx.x, blk = blockIdx.x;
  for (int j = tid; j < NBUCK; j += 512) hist[j] = 0;
  __syncthreads();
  #pragma unroll
  for (int k = 0; k < EB/512; ++k){
    int e = blk*EB + k*512 + tid;
    if (e < N_EDGES){
      int src = eidx[e], dst = eidx[N_EDGES + e];
      float4v f = *(const float4v*)(efeat + (size_t)e*4);
      int t = 0; float b = f[0];
      if (f[1] > b){ b = f[1]; t = 1; }
      if (f[2] > b){ b = f[2]; t = 2; }
      if (f[3] > b){ b = f[3]; t = 3; }
      packed[e] = (src << 2) | t;
      atomicAdd(&cnt[dst*4 + t], 1);
      atomicAdd(&hist[dst >> BSH], 1);
    }
  }
  __syncthreads();
  for (int j = tid; j < NBUCK; j += 512) bcntT[j*NBLKA + blk] = hist[j];
}

// generalized 3-pass exclusive scan (n elements)
__global__ void scan_pass1(const int* __restrict__ src, int* __restrict__ bsum, int n){
  __shared__ int ws[4];
  int tid = threadIdx.x, lane = tid & 63, w = tid >> 6;
  int idx = blockIdx.x*1024 + tid*4;
  int v = 0;
  if (idx + 3 < n){ int4v x = *(const int4v*)(src + idx); v = x[0]+x[1]+x[2]+x[3]; }
  else { for (int k = 0; k < 4; ++k) if (idx + k < n) v += src[idx+k]; }
  for (int d = 32; d; d >>= 1) v += __shfl_down(v, d);
  if (lane == 0) ws[w] = v;
  __syncthreads();
  if (tid == 0) bsum[blockIdx.x] = ws[0]+ws[1]+ws[2]+ws[3];
}

__global__ void scan_pass2(const int* __restrict__ bsum, int* __restrict__ bpre,
                           int* __restrict__ total_out, int nb){
  __shared__ int sh[512];
  int tid = threadIdx.x;
  int v = (tid < nb) ? bsum[tid] : 0;
  sh[tid] = v;
  __syncthreads();
  for (int d = 1; d < 512; d <<= 1){
    int y = (tid >= d) ? sh[tid-d] : 0;
    __syncthreads();
    sh[tid] += y;
    __syncthreads();
  }
  if (tid < nb) bpre[tid] = sh[tid] - v;
  if (tid == 511) *total_out = sh[511];
}

__global__ void scan_pass3(const int* __restrict__ src, const int* __restrict__ bpre,
                           int* __restrict__ off, int n){
  __shared__ int wsum[4];
  int tid = threadIdx.x, lane = tid & 63, w = tid >> 6;
  int idx = blockIdx.x*1024 + tid*4;
  int v0=0,v1=0,v2=0,v3=0;
  if (idx + 3 < n){ int4v x = *(const int4v*)(src + idx); v0=x[0];v1=x[1];v2=x[2];v3=x[3]; }
  else {
    if (idx   < n) v0 = src[idx];
    if (idx+1 < n) v1 = src[idx+1];
    if (idx+2 < n) v2 = src[idx+2];
    if (idx+3 < n) v3 = src[idx+3];
  }
  int ts = v0+v1+v2+v3;
  int sc = ts;
  for (int d = 1; d < 64; d <<= 1){ int y = __shfl_up(sc, d); if (lane >= d) sc += y; }
  if (lane == 63) wsum[w] = sc;
  __syncthreads();
  int wofs = 0;
  for (int k = 0; k < w; ++k) wofs += wsum[k];
  int base = bpre[blockIdx.x] + wofs + sc - ts;
  int e0 = base, e1 = e0+v0, e2 = e1+v1, e3 = e2+v2;
  if (idx   < n) off[idx  ] = e0;
  if (idx+1 < n) off[idx+1] = e1;
  if (idx+2 < n) off[idx+2] = e2;
  if (idx+3 < n) off[idx+3] = e3;
}

// phase A: scatter edges into per-(bucket,block) exclusive runs (line-exclusive writes)
__global__ void bucket_scatter(const int* __restrict__ eidx, const int* __restrict__ packed,
                               const int* __restrict__ boffT, int* __restrict__ bucketed){
  __shared__ int cur[NBUCK];
  int tid = threadIdx.x, blk = blockIdx.x;
  for (int j = tid; j < NBUCK; j += 512) cur[j] = boffT[j*NBLKA + blk];
  __syncthreads();
  #pragma unroll
  for (int k = 0; k < EB/512; ++k){
    int e = blk*EB + k*512 + tid;
    if (e < N_EDGES){
      int dst = eidx[N_EDGES + e];
      int pos = atomicAdd(&cur[dst >> BSH], 1);
      bucketed[pos] = ((dst & ((1<<BSH)-1)) << 19) | packed[e];
    }
  }
}

// phase B: one block per bucket; LDS cursors from off4; scatter to final CSR positions
__global__ void bucket_sort(const int* __restrict__ bucketed, const int* __restrict__ boffT,
                            const int* __restrict__ off4, int* __restrict__ sorted){
  __shared__ int cur[(1<<BSH)*4];
  int tid = threadIdx.x, b = blockIdx.x;
  int base = b * ((1<<BSH)*4);
  for (int j = tid; j < (1<<BSH)*4; j += 512)
    cur[j] = off4[imin(base + j, SCAN_N)];
  __syncthreads();
  int s = boffT[b*NBLKA];
  int e = boffT[(b+1)*NBLKA];
  for (int i = s + tid; i < e; i += 512){
    int w = bucketed[i];
    int ci = ((w >> 19) << 2) | (w & 3);
    int pos = atomicAdd(&cur[ci], 1);
    sorted[pos] = w & 0x7FFFF;
  }
}

// h_bf16 = bf16(node_feat)
__global__ void init_h(const float* __restrict__ nf, ushort_t* __restrict__ hB, int n4){
  int i = blockIdx.x*256 + threadIdx.x;
  if (i >= n4) return;
  float4v v = *(const float4v*)(nf + (size_t)i*4);
  uint2v u;
  u[0] = (uint_t)f2b(v[0]) | ((uint_t)f2b(v[1])<<16);
  u[1] = (uint_t)f2b(v[2]) | ((uint_t)f2b(v[3])<<16);
  *(uint2v*)(hB + (size_t)i*4) = u;
}

// ---------------- per-step kernels ----------------

// Y(Nx512) = hB(Nx128) @ WY^T. Block: 64 rows x 512 cols, 8 waves each 64x64.
// NO LDS, NO barriers: A/B fragments loaded directly from global (A once, B L2-hot).
__launch_bounds__(512, 2)
__global__ void transform_kernel(const ushort_t* __restrict__ hB, const ushort_t* __restrict__ WY,
                                 ushort_t* __restrict__ Y){
  int tid = threadIdx.x, w = tid >> 6, lane = tid & 63;
  int l15 = lane & 15, lq = lane >> 4;
  int row0 = blockIdx.x * 64;
  float4v acc[4][4] = {};
  #pragma unroll
  for (int s = 0; s < 4; ++s){
    int klo = s*32 + lq*8;
    short8 af[4];
    #pragma unroll
    for (int i = 0; i < 4; ++i){
      int node = imin(row0 + i*16 + l15, N_NODES-1);
      af[i] = *reinterpret_cast<const short8*>(hB + (size_t)node*128 + klo);
    }
    #pragma unroll
    for (int j = 0; j < 4; ++j){
      int n = w*64 + j*16 + l15;
      short8 bf = *reinterpret_cast<const short8*>(WY + (size_t)n*128 + klo);
      #pragma unroll
      for (int i = 0; i < 4; ++i)
        acc[i][j] = __builtin_amdgcn_mfma_f32_16x16x32_bf16(af[i], bf, acc[i][j], 0, 0, 0);
    }
  }
  #pragma unroll
  for (int i = 0; i < 4; ++i)
    #pragma unroll
    for (int q = 0; q < 4; ++q){
      int grow = row0 + i*16 + lq*4 + q;
      if (grow >= N_NODES) continue;
      #pragma unroll
      for (int j = 0; j < 4; ++j)
        Y[(size_t)grow*512 + w*64 + j*16 + l15] = f2b(acc[i][j][q]);
    }
}

// one wave per node: a[v] = sum over in-edges of Y[(src<<2)|t] rows + sum_t cnt*b_edge
__global__ void agg_kernel(const int* __restrict__ off4, const int* __restrict__ sorted,
                           const ushort_t* __restrict__ Y, const int* __restrict__ cnt,
                           const float* __restrict__ b_edge, ushort_t* __restrict__ aB){
  int wid = (int)((blockIdx.x * blockDim.x + threadIdx.x) >> 6);
  int lane = threadIdx.x & 63;
  if (wid >= N_NODES) return;
  int s = off4[wid*4], e = off4[wid*4+4];
  int col = lane*2;
  float p0=0,p1=0,q0=0,q1=0,r0=0,r1=0,t0=0,t1=0;
  for (int i = s; i < e; i += 16){
    int vv[16];
    #pragma unroll
    for (int k = 0; k < 16; ++k){
      int j = i + k;
      int sv = sorted[imin(j, e-1)];
      vv[k] = __builtin_amdgcn_readfirstlane(j < e ? sv : ZERO_IDX);
    }
    uint_t hv[16];
    #pragma unroll
    for (int k = 0; k < 16; ++k)
      hv[k] = *(const uint_t*)(Y + (size_t)vv[k]*128 + col);
    #pragma unroll
    for (int k = 0; k < 16; ++k){
      float f0 = bits2f((hv[k] & 0xffffu) << 16);
      float f1 = bits2f(hv[k] & 0xffff0000u);
      if ((k&3)==0){ p0+=f0; p1+=f1; }
      else if ((k&3)==1){ q0+=f0; q1+=f1; }
      else if ((k&3)==2){ r0+=f0; r1+=f1; }
      else { t0+=f0; t1+=f1; }
    }
  }
  float s0 = (p0+q0)+(r0+t0);
  float s1 = (p1+q1)+(r1+t1);
  int4v c4 = *(const int4v*)(cnt + wid*4);
  #pragma unroll
  for (int t = 0; t < 4; ++t){
    float cf = (float)c4[t];
    s0 += cf * b_edge[t*128 + col];
    s1 += cf * b_edge[t*128 + col + 1];
  }
  *(uint_t*)(aB + (size_t)wid*128 + col) = (uint_t)f2b(s0) | ((uint_t)f2b(s1) << 16);
}

// fused GRU: [a|h](64x256) @ W2^T per block (64 rows x 512 gate-cols, 8 waves x 64x64).
// NO LDS; each wave's 16 output cols carry all 4 gates (j=0:r 1:z 2:inn 3:hn) ->
// gate algebra in-register. Zero-blocks skipped (inn: h-side zero, hn: a-side zero).
// One barrier before the in-place hB write (all waves read the block's hB rows as A).
__launch_bounds__(512, 2)
__global__ void gru_kernel(const ushort_t* __restrict__ aB, ushort_t* __restrict__ hB,
                           const ushort_t* __restrict__ W2, const float* __restrict__ b_ih,
                           const float* __restrict__ b_hh, float* __restrict__ hF, int last){
  int tid = threadIdx.x, w = tid >> 6, lane = tid & 63;
  int l15 = lane & 15, lq = lane >> 4;
  int row0 = blockIdx.x * 64;
  float4v acc[4][4] = {};
  #pragma unroll
  for (int s = 0; s < 8; ++s){
    const ushort_t* srcA = (s < 4) ? aB : hB;
    int klo = (s & 3)*32 + lq*8;
    short8 af[4];
    #pragma unroll
    for (int i = 0; i < 4; ++i){
      int node = imin(row0 + i*16 + l15, N_NODES-1);
      af[i] = *reinterpret_cast<const short8*>(srcA + (size_t)node*128 + klo);
    }
    #pragma unroll
    for (int j = 0; j < 4; ++j){
      if ((s < 4) ? (j == 3) : (j == 2)) continue;  // skip known-zero W2 blocks
      int n = w*64 + j*16 + l15;
      short8 bf = *reinterpret_cast<const short8*>(W2 + (size_t)n*256 + s*32 + lq*8);
      #pragma unroll
      for (int i = 0; i < 4; ++i)
        acc[i][j] = __builtin_amdgcn_mfma_f32_16x16x32_bf16(af[i], bf, acc[i][j], 0, 0, 0);
    }
  }
  int c = w*16 + l15;
  float bir = b_ih[c]     + b_hh[c];
  float biz = b_ih[128+c] + b_hh[128+c];
  float bin = b_ih[256+c], bhn = b_hh[256+c];
  __syncthreads();   // all A-reads of hB done before any wave overwrites hB
  #pragma unroll
  for (int i = 0; i < 4; ++i){
    #pragma unroll
    for (int q = 0; q < 4; ++q){
      int grow = row0 + i*16 + lq*4 + q;
      if (grow >= N_NODES) continue;
      float rg = sigm(acc[i][0][q] + bir);
      float zg = sigm(acc[i][1][q] + biz);
      float hn = acc[i][3][q] + bhn;
      float nn = tanh_f(acc[i][2][q] + bin + rg*hn);
      float h = b2f(hB[(size_t)grow*128 + c]);
      float out = (1.0f - zg)*nn + zg*h;
      hB[(size_t)grow*128 + c] = f2b(out);
      if (last) hF[(size_t)grow*128 + c] = out;
    }
  }
}

// ---------------- launch ----------------

extern "C" void kernel_launch(void* const* d_in, const int* in_sizes, int n_in,
                              void* d_out, int out_size, void* d_ws, size_t ws_size,
                              hipStream_t stream) {
  const float* node_feat = (const float*)d_in[0];
  const int*   edge_idx  = (const int*)d_in[1];
  const float* edge_feat = (const float*)d_in[2];
  const float* W_edge    = (const float*)d_in[3];
  const float* b_edge    = (const float*)d_in[4];
  const float* W_ih      = (const float*)d_in[5];
  const float* W_hh      = (const float*)d_in[6];
  const float* b_ih      = (const float*)d_in[7];
  const float* b_hh      = (const float*)d_in[8];
  float* hF = (float*)d_out;

  char* p = (char*)d_ws;
  auto take = [&](size_t bytes) -> char* {
    char* r = p; p += (bytes + 255) & ~(size_t)255; return r;
  };
  ushort_t* WY     = (ushort_t*)take(512*128*2);
  ushort_t* W2     = (ushort_t*)take(512*256*2);
  int* cnt      = (int*)take((size_t)SCAN_N*4);
  int* off4     = (int*)take((size_t)(SCAN_N+1)*4);
  int* bcntT    = (int*)take((size_t)N2*4);
  int* boffT    = (int*)take((size_t)(N2+1)*4);
  int* bsum     = (int*)take(512*4);
  int* bpre     = (int*)take(512*4);
  int* packed   = (int*)take((size_t)N_EDGES*4);
  int* bucketed = (int*)take((size_t)N_EDGES*4);
  int* sorted   = (int*)take((size_t)N_EDGES*4);
  ushort_t* hB = (ushort_t*)take((size_t)N_NODES*128*2);
  ushort_t* Y  = (ushort_t*)take(((size_t)N_NODES*512 + 256)*2);
  ushort_t* aB = (ushort_t*)take((size_t)N_NODES*128*2);

  hipMemsetAsync(cnt, 0, (size_t)SCAN_N*4, stream);
  hipMemsetAsync(Y + (size_t)N_NODES*512, 0, 256*2, stream);  // zero pad row for agg tail

  prep_weights<<<768, 256, 0, stream>>>(W_edge, W_ih, W_hh, WY, W2);
  edge_pass1<<<NBLKA, 512, 0, stream>>>(edge_idx, edge_feat, packed, cnt, bcntT);
  scan_pass1<<<NB1, 256, 0, stream>>>(cnt, bsum, SCAN_N);
  scan_pass2<<<1, 512, 0, stream>>>(bsum, bpre, off4 + SCAN_N, NB1);
  scan_pass3<<<NB1, 256, 0, stream>>>(cnt, bpre, off4, SCAN_N);
  scan_pass1<<<NB2, 256, 0, stream>>>(bcntT, bsum, N2);
  scan_pass2<<<1, 512, 0, stream>>>(bsum, bpre, boffT + N2, NB2);
  scan_pass3<<<NB2, 256, 0, stream>>>(bcntT, bpre, boffT, N2);
  bucket_scatter<<<NBLKA, 512, 0, stream>>>(edge_idx, packed, boffT, bucketed);
  bucket_sort<<<NBUCK, 512, 0, stream>>>(bucketed, boffT, off4, sorted);
  init_h<<<(N_NODES*32 + 255)/256, 256, 0, stream>>>(node_feat, hB, N_NODES*32);

  int gb = (N_NODES + 63) / 64;   // 1563
  for (int step = 0; step < 4; ++step){
    transform_kernel<<<gb, 512, 0, stream>>>(hB, WY, Y);
    agg_kernel<<<(N_NODES+3)/4, 256, 0, stream>>>(off4, sorted, Y, cnt, b_edge, aB);
    gru_kernel<<<gb, 512, 0, stream>>>(aB, hB, W2, b_ih, b_hh, hF, step == 3);
  }
}

// Round 9
// 805.859 us; speedup vs baseline: 1.3931x; 1.3931x over previous
//
#include <hip/hip_runtime.h>

#define N_NODES 100000
#define N_EDGES 1600000
#define HID 128
#define SCAN_N (N_NODES*4)
#define NB1 ((SCAN_N + 1023) / 1024)
#define ZERO_IDX (N_NODES*4)   // gather index of the zero pad row in Y

#define EB 8192                // edges per block in bucket pipeline
#define NBLKA ((N_EDGES + EB - 1) / EB)          // 196
#define BSH 9                  // 512 nodes per bucket
#define NBUCK ((N_NODES + (1<<BSH) - 1) >> BSH)  // 196
#define N2 (NBUCK * NBLKA)
#define NB2 ((N2 + 1023) / 1024)

typedef __attribute__((ext_vector_type(8))) short short8;
typedef __attribute__((ext_vector_type(4))) float float4v;
typedef __attribute__((ext_vector_type(4))) int int4v;
typedef __attribute__((ext_vector_type(2))) unsigned int uint2v;
typedef unsigned short ushort_t;
typedef unsigned int uint_t;

__device__ __forceinline__ float bits2f(uint_t u){ union{uint_t u; float f;} x; x.u=u; return x.f; }
__device__ __forceinline__ float b2f(ushort_t u){ return bits2f(((uint_t)u)<<16); }
__device__ __forceinline__ ushort_t f2b(float f){
  union{float f; uint_t u;} x; x.f=f;
  uint_t r = x.u + 0x7fffu + ((x.u>>16)&1u);
  return (ushort_t)(r>>16);
}
__device__ __forceinline__ float sigm(float x){ return 1.0f/(1.0f+__expf(-x)); }
__device__ __forceinline__ float tanh_f(float x){
  float t=__expf(-2.0f*fabsf(x)); float y=(1.0f-t)/(1.0f+t); return x>=0.f? y : -y;
}
__device__ __forceinline__ int imin(int a, int b){ return a < b ? a : b; }

// ---------------- preprocessing ----------------

// WY[g][d] = W_edge flat (g = t*128+o), [512][128]
// W2[512][256] (R6 layout): n_l -> wn=n_l>>7, j=(n_l>>4)&7, rr=n_l&15;
//   col c = wn*32+(j&1)*16+rr; gate jg=j>>1 (0:r 1:z 2:inn 3:hn);
//   K [0,128)=W_ih side, [128,256)=W_hh side; inn zero on h-side, hn zero on a-side.
__global__ void prep_weights(const float* __restrict__ W_edge, const float* __restrict__ W_ih,
                             const float* __restrict__ W_hh, ushort_t* __restrict__ WY,
                             ushort_t* __restrict__ W2){
  int i = blockIdx.x*256 + threadIdx.x;
  if (i < 65536){
    WY[i] = f2b(W_edge[i]);
  } else if (i < 65536 + 131072){
    int i2 = i - 65536;
    int n_l = i2 >> 8, k = i2 & 255;
    int wn = n_l >> 7, j = (n_l >> 4) & 7, rr = n_l & 15;
    int c = wn*32 + (j&1)*16 + rr;
    int jg = j >> 1;
    float v;
    if (jg < 2)       v = (k < 128) ? W_ih[(jg*128 + c)*128 + k] : W_hh[(jg*128 + c)*128 + (k-128)];
    else if (jg == 2) v = (k < 128) ? W_ih[(256 + c)*128 + k] : 0.0f;
    else              v = (k >= 128) ? W_hh[(256 + c)*128 + (k-128)] : 0.0f;
    W2[n_l*256 + k] = f2b(v);
  }
}

// etype argmax, pack (src<<2)|t, histogram cnt[dst*4+t] and per-block bucket hist
__global__ void edge_pass1(const int* __restrict__ eidx, const float* __restrict__ efeat,
                           int* __restrict__ packed, int* __restrict__ cnt,
                           int* __restrict__ bcntT){
  __shared__ int hist[NBUCK];
  int tid = threadIdx.x, blk = blockIdx.x;
  for (int j = tid; j < NBUCK; j += 512) hist[j] = 0;
  __syncthreads();
  #pragma unroll
  for (int k = 0; k < EB/512; ++k){
    int e = blk*EB + k*512 + tid;
    if (e < N_EDGES){
      int src = eidx[e], dst = eidx[N_EDGES + e];
      float4v f = *(const float4v*)(efeat + (size_t)e*4);
      int t = 0; float b = f[0];
      if (f[1] > b){ b = f[1]; t = 1; }
      if (f[2] > b){ b = f[2]; t = 2; }
      if (f[3] > b){ b = f[3]; t = 3; }
      packed[e] = (src << 2) | t;
      atomicAdd(&cnt[dst*4 + t], 1);
      atomicAdd(&hist[dst >> BSH], 1);
    }
  }
  __syncthreads();
  for (int j = tid; j < NBUCK; j += 512) bcntT[j*NBLKA + blk] = hist[j];
}

// generalized 3-pass exclusive scan (n elements)
__global__ void scan_pass1(const int* __restrict__ src, int* __restrict__ bsum, int n){
  __shared__ int ws[4];
  int tid = threadIdx.x, lane = tid & 63, w = tid >> 6;
  int idx = blockIdx.x*1024 + tid*4;
  int v = 0;
  if (idx + 3 < n){ int4v x = *(const int4v*)(src + idx); v = x[0]+x[1]+x[2]+x[3]; }
  else { for (int k = 0; k < 4; ++k) if (idx + k < n) v += src[idx+k]; }
  for (int d = 32; d; d >>= 1) v += __shfl_down(v, d);
  if (lane == 0) ws[w] = v;
  __syncthreads();
  if (tid == 0) bsum[blockIdx.x] = ws[0]+ws[1]+ws[2]+ws[3];
}

__global__ void scan_pass2(const int* __restrict__ bsum, int* __restrict__ bpre,
                           int* __restrict__ total_out, int nb){
  __shared__ int sh[512];
  int tid = threadIdx.x;
  int v = (tid < nb) ? bsum[tid] : 0;
  sh[tid] = v;
  __syncthreads();
  for (int d = 1; d < 512; d <<= 1){
    int y = (tid >= d) ? sh[tid-d] : 0;
    __syncthreads();
    sh[tid] += y;
    __syncthreads();
  }
  if (tid < nb) bpre[tid] = sh[tid] - v;
  if (tid == 511) *total_out = sh[511];
}

__global__ void scan_pass3(const int* __restrict__ src, const int* __restrict__ bpre,
                           int* __restrict__ off, int n){
  __shared__ int wsum[4];
  int tid = threadIdx.x, lane = tid & 63, w = tid >> 6;
  int idx = blockIdx.x*1024 + tid*4;
  int v0=0,v1=0,v2=0,v3=0;
  if (idx + 3 < n){ int4v x = *(const int4v*)(src + idx); v0=x[0];v1=x[1];v2=x[2];v3=x[3]; }
  else {
    if (idx   < n) v0 = src[idx];
    if (idx+1 < n) v1 = src[idx+1];
    if (idx+2 < n) v2 = src[idx+2];
    if (idx+3 < n) v3 = src[idx+3];
  }
  int ts = v0+v1+v2+v3;
  int sc = ts;
  for (int d = 1; d < 64; d <<= 1){ int y = __shfl_up(sc, d); if (lane >= d) sc += y; }
  if (lane == 63) wsum[w] = sc;
  __syncthreads();
  int wofs = 0;
  for (int k = 0; k < w; ++k) wofs += wsum[k];
  int base = bpre[blockIdx.x] + wofs + sc - ts;
  int e0 = base, e1 = e0+v0, e2 = e1+v1, e3 = e2+v2;
  if (idx   < n) off[idx  ] = e0;
  if (idx+1 < n) off[idx+1] = e1;
  if (idx+2 < n) off[idx+2] = e2;
  if (idx+3 < n) off[idx+3] = e3;
}

// phase A: scatter edges into per-(bucket,block) exclusive runs (line-exclusive writes)
__global__ void bucket_scatter(const int* __restrict__ eidx, const int* __restrict__ packed,
                               const int* __restrict__ boffT, int* __restrict__ bucketed){
  __shared__ int cur[NBUCK];
  int tid = threadIdx.x, blk = blockIdx.x;
  for (int j = tid; j < NBUCK; j += 512) cur[j] = boffT[j*NBLKA + blk];
  __syncthreads();
  #pragma unroll
  for (int k = 0; k < EB/512; ++k){
    int e = blk*EB + k*512 + tid;
    if (e < N_EDGES){
      int dst = eidx[N_EDGES + e];
      int pos = atomicAdd(&cur[dst >> BSH], 1);
      bucketed[pos] = ((dst & ((1<<BSH)-1)) << 19) | packed[e];
    }
  }
}

// phase B: one block per bucket; LDS cursors from off4; scatter to final CSR positions
__global__ void bucket_sort(const int* __restrict__ bucketed, const int* __restrict__ boffT,
                            const int* __restrict__ off4, int* __restrict__ sorted){
  __shared__ int cur[(1<<BSH)*4];
  int tid = threadIdx.x, b = blockIdx.x;
  int base = b * ((1<<BSH)*4);
  for (int j = tid; j < (1<<BSH)*4; j += 512)
    cur[j] = off4[imin(base + j, SCAN_N)];
  __syncthreads();
  int s = boffT[b*NBLKA];
  int e = boffT[(b+1)*NBLKA];
  for (int i = s + tid; i < e; i += 512){
    int w = bucketed[i];
    int ci = ((w >> 19) << 2) | (w & 3);
    int pos = atomicAdd(&cur[ci], 1);
    sorted[pos] = w & 0x7FFFF;
  }
}

// h_bf16 = bf16(node_feat)
__global__ void init_h(const float* __restrict__ nf, ushort_t* __restrict__ hB, int n4){
  int i = blockIdx.x*256 + threadIdx.x;
  if (i >= n4) return;
  float4v v = *(const float4v*)(nf + (size_t)i*4);
  uint2v u;
  u[0] = (uint_t)f2b(v[0]) | ((uint_t)f2b(v[1])<<16);
  u[1] = (uint_t)f2b(v[2]) | ((uint_t)f2b(v[3])<<16);
  *(uint2v*)(hB + (size_t)i*4) = u;
}

// ---------------- per-step kernels ----------------

// Y(Nx512) = hB(Nx128) @ WY^T  (R6-proven LDS-staged structure; runs ONCE before the loop)
__launch_bounds__(512, 2)
__global__ void transform_kernel(const ushort_t* __restrict__ hB, const ushort_t* __restrict__ WY,
                                 ushort_t* __restrict__ Y){
  __shared__ ushort_t lA[128*64];
  __shared__ ushort_t lB[512*64];
  int tid = threadIdx.x, w = tid >> 6, lane = tid & 63;
  int wm = w >> 2, wn = w & 3;
  int row0 = blockIdx.x * 128;
  float4v acc[4][8] = {};
  for (int kt = 0; kt < 2; ++kt){
    short8 va[2], vb[8];
    #pragma unroll
    for (int i = 0; i < 2; ++i){
      int cidx = i*512 + tid;
      int r = cidx >> 3, ch = cidx & 7;
      int node = row0 + r; if (node >= N_NODES) node = N_NODES-1;
      va[i] = *reinterpret_cast<const short8*>(hB + (size_t)node*128 + kt*64 + ch*8);
    }
    #pragma unroll
    for (int i = 0; i < 8; ++i){
      int cidx = i*512 + tid;
      int n = cidx >> 3, ch = cidx & 7;
      vb[i] = *reinterpret_cast<const short8*>(WY + (size_t)n*128 + kt*64 + ch*8);
    }
    __syncthreads();
    #pragma unroll
    for (int i = 0; i < 2; ++i){
      int cidx = i*512 + tid;
      int r = cidx >> 3, ch = cidx & 7;
      *reinterpret_cast<short8*>(lA + r*64 + ((ch ^ (r&7))<<3)) = va[i];
    }
    #pragma unroll
    for (int i = 0; i < 8; ++i){
      int cidx = i*512 + tid;
      int n = cidx >> 3, ch = cidx & 7;
      *reinterpret_cast<short8*>(lB + n*64 + ((ch ^ (n&7))<<3)) = vb[i];
    }
    __syncthreads();
    #pragma unroll
    for (int kk = 0; kk < 2; ++kk){
      int lch = kk*4 + (lane>>4);
      short8 af[4], bf[8];
      #pragma unroll
      for (int i = 0; i < 4; ++i){
        int r = wm*64 + i*16 + (lane&15);
        af[i] = *reinterpret_cast<const short8*>(lA + r*64 + ((lch ^ (r&7))<<3));
      }
      #pragma unroll
      for (int j = 0; j < 8; ++j){
        int n = wn*128 + j*16 + (lane&15);
        bf[j] = *reinterpret_cast<const short8*>(lB + n*64 + ((lch ^ (n&7))<<3));
      }
      #pragma unroll
      for (int i = 0; i < 4; ++i)
        #pragma unroll
        for (int j = 0; j < 8; ++j)
          acc[i][j] = __builtin_amdgcn_mfma_f32_16x16x32_bf16(af[i], bf[j], acc[i][j], 0, 0, 0);
    }
    __syncthreads();
  }
  #pragma unroll
  for (int i = 0; i < 4; ++i)
    #pragma unroll
    for (int j = 0; j < 8; ++j)
      #pragma unroll
      for (int q = 0; q < 4; ++q){
        int grow = row0 + wm*64 + i*16 + (lane>>4)*4 + q;
        if (grow >= N_NODES) continue;
        int colc = wn*128 + j*16 + (lane&15);
        Y[(size_t)grow*512 + colc] = f2b(acc[i][j][q]);
      }
}

// one wave per node: a[v] = sum over in-edges of Y[(src<<2)|t] rows + sum_t cnt*b_edge
__global__ void agg_kernel(const int* __restrict__ off4, const int* __restrict__ sorted,
                           const ushort_t* __restrict__ Y, const int* __restrict__ cnt,
                           const float* __restrict__ b_edge, ushort_t* __restrict__ aB){
  int wid = (int)((blockIdx.x * blockDim.x + threadIdx.x) >> 6);
  int lane = threadIdx.x & 63;
  if (wid >= N_NODES) return;
  int s = off4[wid*4], e = off4[wid*4+4];
  int col = lane*2;
  float p0=0,p1=0,q0=0,q1=0,r0=0,r1=0,t0=0,t1=0;
  for (int i = s; i < e; i += 16){
    int vv[16];
    #pragma unroll
    for (int k = 0; k < 16; ++k){
      int j = i + k;
      int sv = sorted[imin(j, e-1)];
      vv[k] = __builtin_amdgcn_readfirstlane(j < e ? sv : ZERO_IDX);
    }
    uint_t hv[16];
    #pragma unroll
    for (int k = 0; k < 16; ++k)
      hv[k] = *(const uint_t*)(Y + (size_t)vv[k]*128 + col);
    #pragma unroll
    for (int k = 0; k < 16; ++k){
      float f0 = bits2f((hv[k] & 0xffffu) << 16);
      float f1 = bits2f(hv[k] & 0xffff0000u);
      if ((k&3)==0){ p0+=f0; p1+=f1; }
      else if ((k&3)==1){ q0+=f0; q1+=f1; }
      else if ((k&3)==2){ r0+=f0; r1+=f1; }
      else { t0+=f0; t1+=f1; }
    }
  }
  float s0 = (p0+q0)+(r0+t0);
  float s1 = (p1+q1)+(r1+t1);
  int4v c4 = *(const int4v*)(cnt + wid*4);
  #pragma unroll
  for (int t = 0; t < 4; ++t){
    float cf = (float)c4[t];
    s0 += cf * b_edge[t*128 + col];
    s1 += cf * b_edge[t*128 + col + 1];
  }
  *(uint_t*)(aB + (size_t)wid*128 + col) = (uint_t)f2b(s0) | ((uint_t)f2b(s1) << 16);
}

// Fused GRU + next-step transform.
// Phase 1 = R6 gru: [a|h](128x256) @ W2^T, gates in-register, hB update.
// Epilogue also stages new-h bf16 into lB[16384..32768) ([128][128], 16-chunk XOR swz).
// Phase 2 (skipped when last): Y = h_new @ WY^T with A from LDS; WY staged as
// [256][64] tiles (8-chunk XOR swz) into lB[0..16384), 2 col-halves x 2 K-halves.
__launch_bounds__(512, 2)
__global__ void gru_tr_kernel(const ushort_t* __restrict__ aB, ushort_t* __restrict__ hB,
                              const ushort_t* __restrict__ W2, const ushort_t* __restrict__ WY,
                              const float* __restrict__ b_ih, const float* __restrict__ b_hh,
                              float* __restrict__ hF, ushort_t* __restrict__ Y, int last){
  __shared__ ushort_t lA[128*64];
  __shared__ ushort_t lB[512*64];
  int tid = threadIdx.x, w = tid >> 6, lane = tid & 63;
  int wm = w >> 2, wn = w & 3;
  int l15 = lane & 15, lq = lane >> 4;
  int row0 = blockIdx.x * 128;
  {
    float4v acc[4][8] = {};
    for (int kt = 0; kt < 4; ++kt){
      short8 va[2], vb[8];
      const ushort_t* srcA = (kt < 2) ? aB : hB;
      #pragma unroll
      for (int i = 0; i < 2; ++i){
        int cidx = i*512 + tid;
        int r = cidx >> 3, ch = cidx & 7;
        int node = row0 + r; if (node >= N_NODES) node = N_NODES-1;
        va[i] = *reinterpret_cast<const short8*>(srcA + (size_t)node*128 + (kt&1)*64 + ch*8);
      }
      #pragma unroll
      for (int i = 0; i < 8; ++i){
        int cidx = i*512 + tid;
        int n = cidx >> 3, ch = cidx & 7;
        vb[i] = *reinterpret_cast<const short8*>(W2 + (size_t)n*256 + kt*64 + ch*8);
      }
      __syncthreads();
      #pragma unroll
      for (int i = 0; i < 2; ++i){
        int cidx = i*512 + tid;
        int r = cidx >> 3, ch = cidx & 7;
        *reinterpret_cast<short8*>(lA + r*64 + ((ch ^ (r&7))<<3)) = va[i];
      }
      #pragma unroll
      for (int i = 0; i < 8; ++i){
        int cidx = i*512 + tid;
        int n = cidx >> 3, ch = cidx & 7;
        *reinterpret_cast<short8*>(lB + n*64 + ((ch ^ (n&7))<<3)) = vb[i];
      }
      __syncthreads();
      bool lo = (kt < 2);
      #pragma unroll
      for (int kk = 0; kk < 2; ++kk){
        int lch = kk*4 + lq;
        short8 af[4], bf[8];
        #pragma unroll
        for (int i = 0; i < 4; ++i){
          int r = wm*64 + i*16 + l15;
          af[i] = *reinterpret_cast<const short8*>(lA + r*64 + ((lch ^ (r&7))<<3));
        }
        #pragma unroll
        for (int j = 0; j < 8; ++j){
          if (lo ? (j >= 6) : (j == 4 || j == 5)) continue;  // skip known-zero W2 tiles
          int n = wn*128 + j*16 + l15;
          bf[j] = *reinterpret_cast<const short8*>(lB + n*64 + ((lch ^ (n&7))<<3));
          #pragma unroll
          for (int i = 0; i < 4; ++i)
            acc[i][j] = __builtin_amdgcn_mfma_f32_16x16x32_bf16(af[i], bf[j], acc[i][j], 0, 0, 0);
        }
      }
      __syncthreads();
    }
    // epilogue: gates in-register -> hB (+hF if last) + stage new-h into lB_h
    #pragma unroll
    for (int i = 0; i < 4; ++i){
      #pragma unroll
      for (int jj = 0; jj < 2; ++jj){
        int c = wn*32 + jj*16 + l15;
        float bir = b_ih[c] + b_hh[c];
        float biz = b_ih[128+c] + b_hh[128+c];
        float bni = b_ih[256+c], bnh = b_hh[256+c];
        int ch = c >> 3;
        #pragma unroll
        for (int q = 0; q < 4; ++q){
          int row = wm*64 + i*16 + lq*4 + q;
          int grow = row0 + row;
          float rg = sigm(acc[i][0+jj][q] + bir);
          float zg = sigm(acc[i][2+jj][q] + biz);
          float hn = acc[i][6+jj][q] + bnh;
          float nn = tanh_f(acc[i][4+jj][q] + bni + rg*hn);
          int rc = imin(grow, N_NODES-1);
          float h = b2f(hB[(size_t)rc*128 + c]);
          float out = (1.0f - zg)*nn + zg*h;
          ushort_t ob = f2b(out);
          lB[16384 + row*128 + ((ch ^ (row&15))<<3) + (c&7)] = ob;
          if (grow < N_NODES){
            hB[(size_t)grow*128 + c] = ob;
            if (last) hF[(size_t)grow*128 + c] = out;
          }
        }
      }
    }
  }
  if (last) return;
  __syncthreads();   // h tile staged, W2 tile reads done
  // phase 2: Y[row0..row0+127][:] = h_new @ WY^T
  #pragma unroll
  for (int nh = 0; nh < 2; ++nh){
    float4v acc2[4][4] = {};
    #pragma unroll
    for (int kt = 0; kt < 2; ++kt){
      short8 vw[4];
      #pragma unroll
      for (int i = 0; i < 4; ++i){
        int cidx = i*512 + tid;
        int n = cidx >> 3, ch = cidx & 7;
        vw[i] = *reinterpret_cast<const short8*>(WY + (size_t)(nh*256 + n)*128 + kt*64 + ch*8);
      }
      __syncthreads();   // previous MFMA reads of lB_w done
      #pragma unroll
      for (int i = 0; i < 4; ++i){
        int cidx = i*512 + tid;
        int n = cidx >> 3, ch = cidx & 7;
        *reinterpret_cast<short8*>(lB + n*64 + ((ch ^ (n&7))<<3)) = vw[i];
      }
      __syncthreads();
      #pragma unroll
      for (int kk = 0; kk < 2; ++kk){
        int lchh = kt*8 + kk*4 + lq;   // h chunk (K=128, 16 chunks)
        int lchw = kk*4 + lq;          // WY tile chunk (K=64, 8 chunks)
        short8 af[4], bf[4];
        #pragma unroll
        for (int i = 0; i < 4; ++i){
          int r = wm*64 + i*16 + l15;
          af[i] = *reinterpret_cast<const short8*>(lB + 16384 + r*128 + ((lchh ^ (r&15))<<3));
        }
        #pragma unroll
        for (int j = 0; j < 4; ++j){
          int n = wn*64 + j*16 + l15;
          bf[j] = *reinterpret_cast<const short8*>(lB + n*64 + ((lchw ^ (n&7))<<3));
        }
        #pragma unroll
        for (int i = 0; i < 4; ++i)
          #pragma unroll
          for (int j = 0; j < 4; ++j)
            acc2[i][j] = __builtin_amdgcn_mfma_f32_16x16x32_bf16(af[i], bf[j], acc2[i][j], 0, 0, 0);
      }
    }
    #pragma unroll
    for (int i = 0; i < 4; ++i)
      #pragma unroll
      for (int q = 0; q < 4; ++q){
        int grow = row0 + wm*64 + i*16 + lq*4 + q;
        if (grow >= N_NODES) continue;
        #pragma unroll
        for (int j = 0; j < 4; ++j)
          Y[(size_t)grow*512 + nh*256 + wn*64 + j*16 + l15] = f2b(acc2[i][j][q]);
      }
  }
}

// ---------------- launch ----------------

extern "C" void kernel_launch(void* const* d_in, const int* in_sizes, int n_in,
                              void* d_out, int out_size, void* d_ws, size_t ws_size,
                              hipStream_t stream) {
  const float* node_feat = (const float*)d_in[0];
  const int*   edge_idx  = (const int*)d_in[1];
  const float* edge_feat = (const float*)d_in[2];
  const float* W_edge    = (const float*)d_in[3];
  const float* b_edge    = (const float*)d_in[4];
  const float* W_ih      = (const float*)d_in[5];
  const float* W_hh      = (const float*)d_in[6];
  const float* b_ih      = (const float*)d_in[7];
  const float* b_hh      = (const float*)d_in[8];
  float* hF = (float*)d_out;

  char* p = (char*)d_ws;
  auto take = [&](size_t bytes) -> char* {
    char* r = p; p += (bytes + 255) & ~(size_t)255; return r;
  };
  ushort_t* WY     = (ushort_t*)take(512*128*2);
  ushort_t* W2     = (ushort_t*)take(512*256*2);
  int* cnt      = (int*)take((size_t)SCAN_N*4);
  int* off4     = (int*)take((size_t)(SCAN_N+1)*4);
  int* bcntT    = (int*)take((size_t)N2*4);
  int* boffT    = (int*)take((size_t)(N2+1)*4);
  int* bsum     = (int*)take(512*4);
  int* bpre     = (int*)take(512*4);
  int* packed   = (int*)take((size_t)N_EDGES*4);
  int* bucketed = (int*)take((size_t)N_EDGES*4);
  int* sorted   = (int*)take((size_t)N_EDGES*4);
  ushort_t* hB = (ushort_t*)take((size_t)N_NODES*128*2);
  ushort_t* Y  = (ushort_t*)take(((size_t)N_NODES*512 + 256)*2);
  ushort_t* aB = (ushort_t*)take((size_t)N_NODES*128*2);

  hipMemsetAsync(cnt, 0, (size_t)SCAN_N*4, stream);
  hipMemsetAsync(Y + (size_t)N_NODES*512, 0, 256*2, stream);  // zero pad row for agg tail

  prep_weights<<<768, 256, 0, stream>>>(W_edge, W_ih, W_hh, WY, W2);
  edge_pass1<<<NBLKA, 512, 0, stream>>>(edge_idx, edge_feat, packed, cnt, bcntT);
  scan_pass1<<<NB1, 256, 0, stream>>>(cnt, bsum, SCAN_N);
  scan_pass2<<<1, 512, 0, stream>>>(bsum, bpre, off4 + SCAN_N, NB1);
  scan_pass3<<<NB1, 256, 0, stream>>>(cnt, bpre, off4, SCAN_N);
  scan_pass1<<<NB2, 256, 0, stream>>>(bcntT, bsum, N2);
  scan_pass2<<<1, 512, 0, stream>>>(bsum, bpre, boffT + N2, NB2);
  scan_pass3<<<NB2, 256, 0, stream>>>(bcntT, bpre, boffT, N2);
  bucket_scatter<<<NBLKA, 512, 0, stream>>>(edge_idx, packed, boffT, bucketed);
  bucket_sort<<<NBUCK, 512, 0, stream>>>(bucketed, boffT, off4, sorted);
  init_h<<<(N_NODES*32 + 255)/256, 256, 0, stream>>>(node_feat, hB, N_NODES*32);

  int gb = (N_NODES + 127) / 128;   // 782
  transform_kernel<<<gb, 512, 0, stream>>>(hB, WY, Y);
  for (int step = 0; step < 4; ++step){
    agg_kernel<<<(N_NODES+3)/4, 256, 0, stream>>>(off4, sorted, Y, cnt, b_edge, aB);
    gru_tr_kernel<<<gb, 512, 0, stream>>>(aB, hB, W2, WY, b_ih, b_hh, hF, Y, step == 3);
  }
}